// Round 9
// baseline (411.268 us; speedup 1.0000x reference)
//
#include <hip/hip_runtime.h>

#define NN 4096
#define R_RANK 10

typedef __bf16 bf16x8 __attribute__((ext_vector_type(8)));
typedef float floatx4 __attribute__((ext_vector_type(4)));

__device__ __forceinline__ unsigned short f2bf(float f) {
    union { float f; unsigned int u; } v; v.f = f;
    unsigned int r = v.u + 0x7FFFu + ((v.u >> 16) & 1u);   // RNE
    return (unsigned short)(r >> 16);
}
// async global->LDS, 16B per lane; LDS dest = wave-uniform base + lane*16
__device__ __forceinline__ void gll16(const void* g, void* l) {
    __builtin_amdgcn_global_load_lds(
        (const __attribute__((address_space(1))) unsigned int*)g,
        (__attribute__((address_space(3))) unsigned int*)l, 16, 0, 0);
}

// ---------------------------------------------------------------------------
// bf16 MFMA GEMM body (R6 core, unchanged): 128x128 tile, BK=64, 4 waves,
// 4x4 frags, frag-ordered conflict-free LDS, 32 MFMA per barrier-pair.
// OUT: 0 fp32 partials P[bz][M][N]; 1 direct bf16 C[M][N] (EPI 0/1=relu+bias);
//      2 direct bf16 C[N][M] transposed.
// XM: 1 -> M-tile = blockIdx.x (fastest) for XCD L2 A-strip sharing; 0 legacy.
// ---------------------------------------------------------------------------
template<int SK, int OUT, int EPI, int XM>
__device__ __forceinline__ void gemm_body(
    const unsigned short* __restrict__ A, const unsigned short* __restrict__ Bt,
    float* __restrict__ P, unsigned short* __restrict__ C,
    const int M, const int N, const int K, const float* __restrict__ bias,
    unsigned short* As, unsigned short* Bs, const int bx, const int by, const int bz)
{
    const int tid = threadIdx.x;
    const int l = tid & 63, w = tid >> 6;
    const int wy = w >> 1, wx = w & 1;
    const int row0 = (XM ? bx : by) * 128;
    const int col0 = (XM ? by : bx) * 128;
    const int Kc = K / SK;
    const int kb = bz * Kc;
    const int lr = l & 15, lq = l >> 4;

    // wave w stages chunks 2w, 2w+1 of each half. Chunk c lane p holds
    // row c*16+(p&15), k-quad p>>4 -> LDS is exact fragment order.
    const unsigned short* Ag0 = A + (size_t)(row0 + 2 * w * 16 + lr) * K + kb + lq * 8;
    const unsigned short* Ag1 = Ag0 + (size_t)16 * K;
    const unsigned short* Bg0 = Bt + (size_t)(col0 + 2 * w * 16 + lr) * K + kb + lq * 8;
    const unsigned short* Bg1 = Bg0 + (size_t)16 * K;
    char* Asw = (char*)As + 2 * w * 1024;
    char* Bsw = (char*)Bs + 2 * w * 1024;

    floatx4 acc[4][4];
    #pragma unroll
    for (int i = 0; i < 4; ++i)
        #pragma unroll
        for (int j = 0; j < 4; ++j) acc[i][j] = (floatx4){0.f, 0.f, 0.f, 0.f};

    const char* Afr = (const char*)As + wy * 4096 + l * 16;
    const char* Bfr = (const char*)Bs + wx * 4096 + l * 16;

    for (int k0 = 0; k0 < Kc; k0 += 64) {
        __syncthreads();                    // WAR on LDS
        #pragma unroll
        for (int h = 0; h < 2; ++h) {       // half h covers k in [h*32, h*32+32)
            gll16(Ag0 + k0 + h * 32, Asw + h * 8192);
            gll16(Ag1 + k0 + h * 32, Asw + h * 8192 + 1024);
            gll16(Bg0 + k0 + h * 32, Bsw + h * 8192);
            gll16(Bg1 + k0 + h * 32, Bsw + h * 8192 + 1024);
        }
        __syncthreads();                    // drains vmcnt: both halves ready

        #pragma unroll
        for (int h = 0; h < 2; ++h) {
            bf16x8 af[4], bf[4];
            #pragma unroll
            for (int i = 0; i < 4; ++i) af[i] = *(const bf16x8*)(Afr + h * 8192 + i * 1024);
            #pragma unroll
            for (int i = 0; i < 4; ++i) bf[i] = *(const bf16x8*)(Bfr + h * 8192 + i * 1024);
            #pragma unroll
            for (int mf = 0; mf < 4; ++mf)
                #pragma unroll
                for (int nf = 0; nf < 4; ++nf)
                    acc[mf][nf] = __builtin_amdgcn_mfma_f32_16x16x32_bf16(
                        af[mf], bf[nf], acc[mf][nf], 0, 0, 0);
        }
    }

    const int gr0 = row0 + wy * 64 + lq * 4;
    const int gc0 = col0 + wx * 64 + lr;
    if constexpr (OUT == 0) {
        float* Pz = P + (size_t)bz * M * N;
        #pragma unroll
        for (int mf = 0; mf < 4; ++mf)
            #pragma unroll
            for (int nf = 0; nf < 4; ++nf)
                #pragma unroll
                for (int r = 0; r < 4; ++r)
                    Pz[(size_t)(gr0 + mf * 16 + r) * N + gc0 + nf * 16] = acc[mf][nf][r];
    } else if constexpr (OUT == 1) {
        float bb[4];
        #pragma unroll
        for (int nf = 0; nf < 4; ++nf)
            if constexpr (EPI == 1) bb[nf] = bias[gc0 + nf * 16];
        #pragma unroll
        for (int mf = 0; mf < 4; ++mf)
            #pragma unroll
            for (int nf = 0; nf < 4; ++nf)
                #pragma unroll
                for (int r = 0; r < 4; ++r) {
                    float x = acc[mf][nf][r];
                    if constexpr (EPI == 1) x = fmaxf(x + bb[nf], 0.f);
                    C[(size_t)(gr0 + mf * 16 + r) * N + gc0 + nf * 16] = f2bf(x);
                }
    } else {
        #pragma unroll
        for (int mf = 0; mf < 4; ++mf)
            #pragma unroll
            for (int nf = 0; nf < 4; ++nf) {
                ushort4 p;
                p.x = f2bf(acc[mf][nf][0]); p.y = f2bf(acc[mf][nf][1]);
                p.z = f2bf(acc[mf][nf][2]); p.w = f2bf(acc[mf][nf][3]);
                *(ushort4*)&C[(size_t)(gc0 + nf * 16) * M + gr0 + mf * 16] = p;
            }
    }
}

template<int SK, int OUT, int EPI, int XM>
__global__ __launch_bounds__(256) void gemm_mfma(
    const unsigned short* __restrict__ A, const unsigned short* __restrict__ Bt,
    float* __restrict__ P, unsigned short* __restrict__ C,
    const int M, const int N, const int K, const float* __restrict__ bias)
{
    __shared__ __align__(16) unsigned short As[8192];
    __shared__ __align__(16) unsigned short Bs[8192];
    gemm_body<SK, OUT, EPI, XM>(A, Bt, P, C, M, N, K, bias, As, Bs,
                                blockIdx.x, blockIdx.y, blockIdx.z);
}

// ---------------------------------------------------------------------------
// Node 1: prep (z 0..3: weight transposes + x cvt) | row_stats (z == 4).
// No max-shift: scores <= ~20 -> exp <= 5e8, rowsum <= 2e12, fp32-safe.
// row_stats also zeroes deg and the finalize counter.
// ---------------------------------------------------------------------------
__global__ __launch_bounds__(256) void prep_rs_kernel(
    const float* __restrict__ x, const float* __restrict__ w_map,
    const float* __restrict__ w1, const float* __restrict__ w2,
    unsigned short* __restrict__ xb, unsigned short* __restrict__ wmT,
    unsigned short* __restrict__ w1T, unsigned short* __restrict__ w2T,
    const float* __restrict__ nv1, const float* __restrict__ nv2,
    float* __restrict__ rowsum, float* __restrict__ deg,
    unsigned int* __restrict__ counter)
{
    const int z = blockIdx.z;
    const int tid = threadIdx.x;
    if (z == 4) {   // row_stats: 1024 logical blocks, 4 rows each
        const int rsid = blockIdx.x + blockIdx.y * 32;
        const int i0 = rsid * 4;
        if (rsid < 16) deg[rsid * 256 + tid] = 0.f;
        if (rsid == 16 && tid == 0) *counter = 0u;
        __shared__ float a[4][R_RANK];
        if (tid < 4 * R_RANK) a[tid / R_RANK][tid % R_RANK] = nv1[i0 * R_RANK + tid];
        __syncthreads();
        float sm[4] = {0.f, 0.f, 0.f, 0.f};
        #pragma unroll
        for (int t = 0; t < 16; ++t) {
            const int j = t * 256 + tid;
            float v[R_RANK];
            #pragma unroll
            for (int r = 0; r < R_RANK; ++r) v[r] = nv2[r * NN + j];
            #pragma unroll
            for (int q = 0; q < 4; ++q) {
                float acc = 0.f;
                #pragma unroll
                for (int r = 0; r < R_RANK; ++r) acc = fmaf(a[q][r], v[r], acc);
                sm[q] += __expf(fmaxf(acc, 0.f));
            }
        }
        __shared__ float red[4][4];
        #pragma unroll
        for (int q = 0; q < 4; ++q) {
            float m = sm[q];
            #pragma unroll
            for (int off = 32; off > 0; off >>= 1) m += __shfl_down(m, off, 64);
            if ((tid & 63) == 0) red[q][tid >> 6] = m;
        }
        __syncthreads();
        if (tid < 4)
            rowsum[i0 + tid] = red[tid][0] + red[tid][1] + red[tid][2] + red[tid][3];
        return;
    }
    if (z == 3) {   // cvt x -> bf16
        const int b = blockIdx.x + blockIdx.y * 32;
        const size_t base = (size_t)b * 4096 + (size_t)tid * 16;
        #pragma unroll
        for (int i = 0; i < 2; ++i) {
            const float4 a0 = *(const float4*)(x + base + i * 8);
            const float4 a1 = *(const float4*)(x + base + i * 8 + 4);
            ushort4 p, q;
            p.x = f2bf(a0.x); p.y = f2bf(a0.y); p.z = f2bf(a0.z); p.w = f2bf(a0.w);
            q.x = f2bf(a1.x); q.y = f2bf(a1.y); q.z = f2bf(a1.z); q.w = f2bf(a1.w);
            *(ushort4*)(xb + base + i * 8) = p;
            *(ushort4*)(xb + base + i * 8 + 4) = q;
        }
        return;
    }
    const float* W = (z == 0) ? w_map : (z == 1) ? w1 : w2;
    unsigned short* WT = (z == 0) ? wmT : (z == 1) ? w1T : w2T;
    const int CN = (z == 2) ? 512 : 1024;
    if (blockIdx.x * 32 >= CN) return;
    __shared__ float s[32][33];
    const int tx = tid & 31, ty = tid >> 5;
    const int r0 = blockIdx.y * 32, c0 = blockIdx.x * 32;
    #pragma unroll
    for (int i = 0; i < 4; ++i)
        s[ty + 8 * i][tx] = W[(size_t)(r0 + ty + 8 * i) * CN + c0 + tx];
    __syncthreads();
    #pragma unroll
    for (int i = 0; i < 4; ++i)
        WT[(size_t)(c0 + ty + 8 * i) * 1024 + r0 + tx] = f2bf(s[tx][ty + 8 * i]);
}

// ---------------------------------------------------------------------------
// Node 2: col degree
// ---------------------------------------------------------------------------
__global__ __launch_bounds__(256) void col_sum_kernel(
    const float* __restrict__ nv1, const float* __restrict__ nv2,
    const float* __restrict__ rowsum, float* __restrict__ deg)
{
    const int j = blockIdx.x * 256 + threadIdx.x;
    const int i0 = blockIdx.y * 256;
    float v[R_RANK];
    #pragma unroll
    for (int r = 0; r < R_RANK; ++r) v[r] = nv2[r * NN + j];
    float acc = 0.f;
    for (int i = i0; i < i0 + 256; ++i) {
        float s = 0.f;
        #pragma unroll
        for (int r = 0; r < R_RANK; ++r) s = fmaf(nv1[i * R_RANK + r], v[r], s);
        acc += __expf(fmaxf(s, 0.f)) * (1.0f / rowsum[i]);
    }
    atomicAdd(&deg[j], acc);
}

// ---------------------------------------------------------------------------
// Node 3: G1 (blocks 0..255) | an_build (blocks 256..8447) — independent
// chains fused into one dispatch; an_build backfills around G1.
// ---------------------------------------------------------------------------
__global__ __launch_bounds__(256) void an_g1_kernel(
    const float* __restrict__ nv1, const float* __restrict__ nv2,
    const float* __restrict__ rowsum, const float* __restrict__ deg,
    unsigned short* __restrict__ AnT,
    const unsigned short* __restrict__ xb, const unsigned short* __restrict__ wmT,
    unsigned short* __restrict__ xm, const float* __restrict__ b_map)
{
    __shared__ __align__(16) unsigned short As[8192];
    __shared__ __align__(16) unsigned short Bs[8192];
    const int id = blockIdx.x;
    if (id < 256) {   // G1: xm = relu(x @ w_map + b), M4096 N1024 K1024
        gemm_body<1, 1, 1, 1>(xb, wmT, nullptr, xm, 4096, 1024, 1024, b_map,
                              As, Bs, id & 31, id >> 5, 0);
        return;
    }
    // an_build: AnT[i][j] = (adp[j][i] + (i==j)) * dinv(i) * dinv(j)
    const int aid = id - 256;
    const int tid = threadIdx.x;
    const int j = (aid & 15) * 256 + tid;
    const int i0 = (aid >> 4) * 8;
    float* v2s = (float*)As;          // [8][R_RANK], reuse GEMM LDS
    float* dis = (float*)As + 8 * R_RANK;
    if (tid < 8 * R_RANK) {
        const int r = tid / 8, t = tid % 8;
        v2s[t * R_RANK + r] = nv2[r * NN + i0 + t];
    }
    if (tid < 8) dis[tid] = rsqrtf(1.0f + deg[i0 + tid]);

    float a[R_RANK];
    #pragma unroll
    for (int r = 0; r < R_RANK; ++r) a[r] = nv1[j * R_RANK + r];
    const float rs = 1.0f / rowsum[j];
    const float dj = rsqrtf(1.0f + deg[j]);
    __syncthreads();

    #pragma unroll
    for (int t = 0; t < 8; ++t) {
        const int i = i0 + t;
        float s = 0.f;
        #pragma unroll
        for (int r = 0; r < R_RANK; ++r) s = fmaf(a[r], v2s[t * R_RANK + r], s);
        const float adp = __expf(fmaxf(s, 0.f)) * rs;
        const float val = (adp + ((i == j) ? 1.f : 0.f)) * dis[t] * dj;
        AnT[(size_t)i * NN + j] = f2bf(val);
    }
}

// ---------------------------------------------------------------------------
// Split-K reduce + bn1(relu(x+b)) -> bf16 (params col-indexed)
// ---------------------------------------------------------------------------
template<int S, int NC>
__global__ __launch_bounds__(256) void reduce_bn_kernel(
    const float* __restrict__ P, unsigned short* __restrict__ out, const int MN,
    const float* __restrict__ bias, const float* __restrict__ gamma,
    const float* __restrict__ beta, const float* __restrict__ mean,
    const float* __restrict__ var)
{
    const int idx = blockIdx.x * 256 + threadIdx.x;   // float4 index
    const int n4 = MN >> 2;
    const float4* Pv = (const float4*)P;
    float4 v = Pv[idx];
    #pragma unroll
    for (int z = 1; z < S; ++z) {
        const float4 t = Pv[idx + (size_t)z * n4];
        v.x += t.x; v.y += t.y; v.z += t.z; v.w += t.w;
    }
    float vals[4] = {v.x, v.y, v.z, v.w};
    const int c0 = (idx << 2) & (NC - 1);
    const float4 b4 = *(const float4*)(bias + c0);
    const float4 g4 = *(const float4*)(gamma + c0);
    const float4 e4 = *(const float4*)(beta + c0);
    const float4 m4 = *(const float4*)(mean + c0);
    const float4 v4 = *(const float4*)(var + c0);
    const float bb[4] = {b4.x, b4.y, b4.z, b4.w};
    const float gg[4] = {g4.x, g4.y, g4.z, g4.w};
    const float ee[4] = {e4.x, e4.y, e4.z, e4.w};
    const float mm[4] = {m4.x, m4.y, m4.z, m4.w};
    const float vv[4] = {v4.x, v4.y, v4.z, v4.w};
    ushort4 p;
    unsigned short* pp = (unsigned short*)&p;
    #pragma unroll
    for (int j = 0; j < 4; ++j) {
        const float sc = gg[j] * rsqrtf(vv[j] + 1e-5f);
        const float sh = ee[j] - mm[j] * sc;
        pp[j] = f2bf(fmaf(fmaxf(vals[j] + bb[j], 0.f), sc, sh));
    }
    *(ushort4*)(out + ((size_t)idx << 2)) = p;
}

// ---------------------------------------------------------------------------
// Node 9: split-K reduce + bn2(relu(x+b)) + mean-pool + last-block finalize.
// One block per channel row (512). pooled accessed ONLY via atomics (cross-XCD
// false-sharing safe); counter gives the grid-completion signal.
// ---------------------------------------------------------------------------
template<int S>
__global__ __launch_bounds__(256) void reduce_pool_fin(
    const float* __restrict__ P, float* __restrict__ pooled,
    unsigned int* __restrict__ counter,
    const float* __restrict__ bias, const float* __restrict__ gamma,
    const float* __restrict__ beta, const float* __restrict__ mean,
    const float* __restrict__ var,
    const float* __restrict__ w_attn, const float* __restrict__ b_attn,
    float* __restrict__ out)
{
    const int row = blockIdx.x;    // 0..511
    const int tid = threadIdx.x;
    constexpr int n4 = 512 * 4096 / 4;
    const float4* Pv = (const float4*)P;
    const float b0 = bias[row];
    float s = 0.f;
    #pragma unroll
    for (int c = 0; c < 4; ++c) {
        const int i4 = row * 1024 + c * 256 + tid;
        float4 v = Pv[i4];
        #pragma unroll
        for (int z = 1; z < S; ++z) {
            const float4 t = Pv[i4 + (size_t)z * n4];
            v.x += t.x; v.y += t.y; v.z += t.z; v.w += t.w;
        }
        s += fmaxf(v.x + b0, 0.f) + fmaxf(v.y + b0, 0.f)
           + fmaxf(v.z + b0, 0.f) + fmaxf(v.w + b0, 0.f);
    }
    #pragma unroll
    for (int off = 32; off > 0; off >>= 1) s += __shfl_down(s, off, 64);
    __shared__ float red[4];
    __shared__ int last;
    if ((tid & 63) == 0) red[tid >> 6] = s;
    __syncthreads();
    if (tid == 0) {
        const float tot = red[0] + red[1] + red[2] + red[3];
        const float sc = gamma[row] * rsqrtf(var[row] + 1e-5f);
        const float sh = beta[row] - mean[row] * sc;
        atomicExch(&pooled[row], fmaf(sc, tot * (1.0f / 4096.0f), sh));
        __threadfence();
        last = (atomicAdd(counter, 1u) == 511u);
    }
    __syncthreads();
    if (!last) return;
    // finalize: attn = sigmoid(pooled . w_attn + b); out = pooled * attn
    __threadfence();
    const float p0 = atomicAdd(&pooled[tid], 0.f);          // coherent read
    const float p1 = atomicAdd(&pooled[tid + 256], 0.f);
    float part = p0 * w_attn[tid] + p1 * w_attn[tid + 256];
    #pragma unroll
    for (int off = 32; off > 0; off >>= 1) part += __shfl_down(part, off, 64);
    __shared__ float red2[4];
    __shared__ float attn_s;
    if ((tid & 63) == 0) red2[tid >> 6] = part;
    __syncthreads();
    if (tid == 0) {
        const float dot = red2[0] + red2[1] + red2[2] + red2[3];
        attn_s = 1.0f / (1.0f + __expf(-(dot + b_attn[0])));
    }
    __syncthreads();
    out[tid] = p0 * attn_s;
    out[tid + 256] = p1 * attn_s;
}

// ---------------------------------------------------------------------------
extern "C" void kernel_launch(void* const* d_in, const int* in_sizes, int n_in,
                              void* d_out, int out_size, void* d_ws, size_t ws_size,
                              hipStream_t stream) {
    const float* x      = (const float*)d_in[0];
    const float* w_map  = (const float*)d_in[1];
    const float* b_map  = (const float*)d_in[2];
    const float* nv1    = (const float*)d_in[3];
    const float* nv2    = (const float*)d_in[4];
    const float* w1     = (const float*)d_in[5];
    const float* b1     = (const float*)d_in[6];
    const float* w2     = (const float*)d_in[7];
    const float* b2     = (const float*)d_in[8];
    const float* bn1_g  = (const float*)d_in[9];
    const float* bn1_b  = (const float*)d_in[10];
    const float* bn1_m  = (const float*)d_in[11];
    const float* bn1_v  = (const float*)d_in[12];
    const float* bn2_g  = (const float*)d_in[13];
    const float* bn2_b  = (const float*)d_in[14];
    const float* bn2_m  = (const float*)d_in[15];
    const float* bn2_v  = (const float*)d_in[16];
    const float* w_attn = (const float*)d_in[17];
    const float* b_attn = (const float*)d_in[18];
    float* out = (float*)d_out;

    // workspace (~85.1 MB), aliasing lifetime-checked:
    const size_t MB = 1024 * 1024;
    char* ws = (char*)d_ws;
    unsigned short* AnT = (unsigned short*)(ws);                  // [0,32M)
    float*          P   = (float*)(ws + 32 * MB);                 // [32M,64M) partials
    char* B0 = ws + 64 * MB;
    unsigned short* xb  = (unsigned short*)(B0);                  // 8 MB, dead after G1
    unsigned short* t1T = (unsigned short*)(B0);                  //   reuse, dead after G3
    unsigned short* t2T = (unsigned short*)(B0);                  //   reuse after G3
    unsigned short* xm  = (unsigned short*)(B0 + 8 * MB);         // 8 MB, dead after G2
    unsigned short* h1  = (unsigned short*)(B0 + 8 * MB);         //   reuse, dead after G4
    unsigned short* wmT = (unsigned short*)(B0 + 16 * MB);        // 2 MB
    unsigned short* w1T = (unsigned short*)(B0 + 18 * MB);        // 2 MB
    unsigned short* w2T = (unsigned short*)(B0 + 20 * MB);        // 1 MB
    float* deg    = (float*)(B0 + 21 * MB);
    float* rowsum = deg + 4096;
    float* pooled = rowsum + 4096;
    unsigned int* counter = (unsigned int*)(pooled + 512);

    // N1: prep | row_stats (also zeroes deg + counter)
    prep_rs_kernel<<<dim3(32, 32, 5), 256, 0, stream>>>(
        x, w_map, w1, w2, xb, wmT, w1T, w2T, nv1, nv2, rowsum, deg, counter);
    // N2: col degree
    col_sum_kernel<<<dim3(16, 16), 256, 0, stream>>>(nv1, nv2, rowsum, deg);
    // N3: G1 (256 blocks) | an_build (8192 blocks)
    an_g1_kernel<<<8448, 256, 0, stream>>>(
        nv1, nv2, rowsum, deg, AnT, xb, wmT, xm, b_map);
    // N4: G2: t1T = (xm @ w1)^T   M4096 N1024 K1024, direct transposed
    gemm_mfma<1, 2, 0, 1><<<dim3(32, 8, 1), 256, 0, stream>>>(
        xm, w1T, nullptr, t1T, 4096, 1024, 1024, nullptr);
    // N5: G3: AnT @ t1 partials   M4096 N1024 K4096, SK2 (512 blocks)
    gemm_mfma<2, 0, 0, 1><<<dim3(32, 8, 2), 256, 0, stream>>>(
        AnT, t1T, P, nullptr, 4096, 1024, 4096, nullptr);
    // N6: h1 = bn1(relu(sum + b1))
    reduce_bn_kernel<2, 1024><<<4096, 256, 0, stream>>>(
        P, h1, 4194304, b1, bn1_g, bn1_b, bn1_m, bn1_v);
    // N7: G4 (swapped): t2T = w2T @ h1^T   M512 N4096 K1024, direct (128 blocks)
    gemm_mfma<1, 1, 0, 0><<<dim3(32, 4, 1), 256, 0, stream>>>(
        w2T, h1, nullptr, t2T, 512, 4096, 1024, nullptr);
    // N8: G5 (swapped): t2T @ AnT^T partials   M512 N4096 K4096, SK4 (512 blocks)
    gemm_mfma<4, 0, 0, 0><<<dim3(32, 4, 4), 256, 0, stream>>>(
        t2T, AnT, P, nullptr, 512, 4096, 4096, nullptr);
    // N9: bn2 + mean-pool + last-block attention finalize
    reduce_pool_fin<4><<<512, 256, 0, stream>>>(
        P, pooled, counter, b2, bn2_g, bn2_b, bn2_m, bn2_v, w_attn, b_attn, out);
}

// Round 12
// 398.578 us; speedup vs baseline: 1.0318x; 1.0318x over previous
//
#include <hip/hip_runtime.h>

#define NN 4096
#define R_RANK 10

typedef __bf16 bf16x8 __attribute__((ext_vector_type(8)));
typedef float floatx4 __attribute__((ext_vector_type(4)));

__device__ __forceinline__ unsigned short f2bf(float f) {
    union { float f; unsigned int u; } v; v.f = f;
    unsigned int r = v.u + 0x7FFFu + ((v.u >> 16) & 1u);   // RNE
    return (unsigned short)(r >> 16);
}
// async global->LDS, 16B per lane; LDS dest = wave-uniform base + lane*16
__device__ __forceinline__ void gll16(const void* g, void* l) {
    __builtin_amdgcn_global_load_lds(
        (const __attribute__((address_space(1))) unsigned int*)g,
        (__attribute__((address_space(3))) unsigned int*)l, 16, 0, 0);
}

// ---------------------------------------------------------------------------
// bf16 MFMA GEMM body (R6 core): 128x128, BK=64, 4 waves, 4x4 frags,
// frag-ordered conflict-free LDS, 32 MFMA per barrier-pair.
// OUT: 0 fp32 partials P[bz][M][N]; 1 direct bf16 C[M][N] (EPI1 relu+bias);
//      2 direct bf16 C[N][M] transposed.
// XM=1: row-tile = blockIdx.x (fastest) -> all XCDs stream the same A rows in
// lockstep; L3 absorbs cross-XCD re-reads (R9: G3 FETCH 135->49 MB).
// ---------------------------------------------------------------------------
template<int SK, int OUT, int EPI, int XM>
__global__ __launch_bounds__(256) void gemm_mfma(
    const unsigned short* __restrict__ A, const unsigned short* __restrict__ Bt,
    float* __restrict__ P, unsigned short* __restrict__ C,
    const int M, const int N, const int K, const float* __restrict__ bias)
{
    __shared__ __align__(16) unsigned short As[8192];
    __shared__ __align__(16) unsigned short Bs[8192];
    const int tid = threadIdx.x;
    const int l = tid & 63, w = tid >> 6;
    const int wy = w >> 1, wx = w & 1;
    const int row0 = (XM ? blockIdx.x : blockIdx.y) * 128;
    const int col0 = (XM ? blockIdx.y : blockIdx.x) * 128;
    const int Kc = K / SK;
    const int kb = blockIdx.z * Kc;
    const int lr = l & 15, lq = l >> 4;

    // wave w stages chunks 2w, 2w+1 of each half. Chunk c lane p holds
    // row c*16+(p&15), k-quad p>>4 -> LDS is exact fragment order.
    const unsigned short* Ag0 = A + (size_t)(row0 + 2 * w * 16 + lr) * K + kb + lq * 8;
    const unsigned short* Ag1 = Ag0 + (size_t)16 * K;
    const unsigned short* Bg0 = Bt + (size_t)(col0 + 2 * w * 16 + lr) * K + kb + lq * 8;
    const unsigned short* Bg1 = Bg0 + (size_t)16 * K;
    char* Asw = (char*)As + 2 * w * 1024;
    char* Bsw = (char*)Bs + 2 * w * 1024;

    floatx4 acc[4][4];
    #pragma unroll
    for (int i = 0; i < 4; ++i)
        #pragma unroll
        for (int j = 0; j < 4; ++j) acc[i][j] = (floatx4){0.f, 0.f, 0.f, 0.f};

    const char* Afr = (const char*)As + wy * 4096 + l * 16;
    const char* Bfr = (const char*)Bs + wx * 4096 + l * 16;

    for (int k0 = 0; k0 < Kc; k0 += 64) {
        __syncthreads();                    // WAR on LDS
        #pragma unroll
        for (int h = 0; h < 2; ++h) {
            gll16(Ag0 + k0 + h * 32, Asw + h * 8192);
            gll16(Ag1 + k0 + h * 32, Asw + h * 8192 + 1024);
            gll16(Bg0 + k0 + h * 32, Bsw + h * 8192);
            gll16(Bg1 + k0 + h * 32, Bsw + h * 8192 + 1024);
        }
        __syncthreads();                    // drains vmcnt: both halves ready

        #pragma unroll
        for (int h = 0; h < 2; ++h) {
            bf16x8 af[4], bf[4];
            #pragma unroll
            for (int i = 0; i < 4; ++i) af[i] = *(const bf16x8*)(Afr + h * 8192 + i * 1024);
            #pragma unroll
            for (int i = 0; i < 4; ++i) bf[i] = *(const bf16x8*)(Bfr + h * 8192 + i * 1024);
            #pragma unroll
            for (int mf = 0; mf < 4; ++mf)
                #pragma unroll
                for (int nf = 0; nf < 4; ++nf)
                    acc[mf][nf] = __builtin_amdgcn_mfma_f32_16x16x32_bf16(
                        af[mf], bf[nf], acc[mf][nf], 0, 0, 0);
        }
    }

    const int gr0 = row0 + wy * 64 + lq * 4;
    const int gc0 = col0 + wx * 64 + lr;
    if constexpr (OUT == 0) {
        float* Pz = P + (size_t)blockIdx.z * M * N;
        #pragma unroll
        for (int mf = 0; mf < 4; ++mf)
            #pragma unroll
            for (int nf = 0; nf < 4; ++nf)
                #pragma unroll
                for (int r = 0; r < 4; ++r)
                    Pz[(size_t)(gr0 + mf * 16 + r) * N + gc0 + nf * 16] = acc[mf][nf][r];
    } else if constexpr (OUT == 1) {
        float bb[4];
        #pragma unroll
        for (int nf = 0; nf < 4; ++nf)
            if constexpr (EPI == 1) bb[nf] = bias[gc0 + nf * 16];
        #pragma unroll
        for (int mf = 0; mf < 4; ++mf)
            #pragma unroll
            for (int nf = 0; nf < 4; ++nf)
                #pragma unroll
                for (int r = 0; r < 4; ++r) {
                    float x = acc[mf][nf][r];
                    if constexpr (EPI == 1) x = fmaxf(x + bb[nf], 0.f);
                    C[(size_t)(gr0 + mf * 16 + r) * N + gc0 + nf * 16] = f2bf(x);
                }
    } else {
        #pragma unroll
        for (int mf = 0; mf < 4; ++mf)
            #pragma unroll
            for (int nf = 0; nf < 4; ++nf) {
                ushort4 p;
                p.x = f2bf(acc[mf][nf][0]); p.y = f2bf(acc[mf][nf][1]);
                p.z = f2bf(acc[mf][nf][2]); p.w = f2bf(acc[mf][nf][3]);
                *(ushort4*)&C[(size_t)(gc0 + nf * 16) * M + gr0 + mf * 16] = p;
            }
    }
}

// ---------------------------------------------------------------------------
// N1: prep (z 0..3) | row_stats (z == 4). Also zeroes deg + finalize counter.
// No max-shift: scores <= ~20 -> exp <= 5e8, rowsum <= 2e12, fp32-safe.
// ---------------------------------------------------------------------------
__global__ __launch_bounds__(256) void prep_rs_kernel(
    const float* __restrict__ x, const float* __restrict__ w_map,
    const float* __restrict__ w1, const float* __restrict__ w2,
    unsigned short* __restrict__ xb, unsigned short* __restrict__ wmT,
    unsigned short* __restrict__ w1T, unsigned short* __restrict__ w2T,
    const float* __restrict__ nv1, const float* __restrict__ nv2,
    float* __restrict__ rowsum, float* __restrict__ deg,
    unsigned int* __restrict__ counter)
{
    const int z = blockIdx.z;
    const int tid = threadIdx.x;
    if (z == 4) {   // row_stats: 1024 logical blocks, 4 rows each
        const int rsid = blockIdx.x + blockIdx.y * 32;
        const int i0 = rsid * 4;
        if (rsid < 16) deg[rsid * 256 + tid] = 0.f;
        if (rsid == 16 && tid == 0) *counter = 0u;
        __shared__ float a[4][R_RANK];
        if (tid < 4 * R_RANK) a[tid / R_RANK][tid % R_RANK] = nv1[i0 * R_RANK + tid];
        __syncthreads();
        float sm[4] = {0.f, 0.f, 0.f, 0.f};
        #pragma unroll
        for (int t = 0; t < 16; ++t) {
            const int j = t * 256 + tid;
            float v[R_RANK];
            #pragma unroll
            for (int r = 0; r < R_RANK; ++r) v[r] = nv2[r * NN + j];
            #pragma unroll
            for (int q = 0; q < 4; ++q) {
                float acc = 0.f;
                #pragma unroll
                for (int r = 0; r < R_RANK; ++r) acc = fmaf(a[q][r], v[r], acc);
                sm[q] += __expf(fmaxf(acc, 0.f));
            }
        }
        __shared__ float red[4][4];
        #pragma unroll
        for (int q = 0; q < 4; ++q) {
            float m = sm[q];
            #pragma unroll
            for (int off = 32; off > 0; off >>= 1) m += __shfl_down(m, off, 64);
            if ((tid & 63) == 0) red[q][tid >> 6] = m;
        }
        __syncthreads();
        if (tid < 4)
            rowsum[i0 + tid] = red[tid][0] + red[tid][1] + red[tid][2] + red[tid][3];
        return;
    }
    if (z == 3) {   // cvt x -> bf16
        const int b = blockIdx.x + blockIdx.y * 32;
        const size_t base = (size_t)b * 4096 + (size_t)tid * 16;
        #pragma unroll
        for (int i = 0; i < 2; ++i) {
            const float4 a0 = *(const float4*)(x + base + i * 8);
            const float4 a1 = *(const float4*)(x + base + i * 8 + 4);
            ushort4 p, q;
            p.x = f2bf(a0.x); p.y = f2bf(a0.y); p.z = f2bf(a0.z); p.w = f2bf(a0.w);
            q.x = f2bf(a1.x); q.y = f2bf(a1.y); q.z = f2bf(a1.z); q.w = f2bf(a1.w);
            *(ushort4*)(xb + base + i * 8) = p;
            *(ushort4*)(xb + base + i * 8 + 4) = q;
        }
        return;
    }
    const float* W = (z == 0) ? w_map : (z == 1) ? w1 : w2;
    unsigned short* WT = (z == 0) ? wmT : (z == 1) ? w1T : w2T;
    const int CN = (z == 2) ? 512 : 1024;
    if (blockIdx.x * 32 >= CN) return;
    __shared__ float s[32][33];
    const int tx = tid & 31, ty = tid >> 5;
    const int r0 = blockIdx.y * 32, c0 = blockIdx.x * 32;
    #pragma unroll
    for (int i = 0; i < 4; ++i)
        s[ty + 8 * i][tx] = W[(size_t)(r0 + ty + 8 * i) * CN + c0 + tx];
    __syncthreads();
    #pragma unroll
    for (int i = 0; i < 4; ++i)
        WT[(size_t)(c0 + ty + 8 * i) * 1024 + r0 + tx] = f2bf(s[tx][ty + 8 * i]);
}

// ---------------------------------------------------------------------------
// N2: col degree
// ---------------------------------------------------------------------------
__global__ __launch_bounds__(256) void col_sum_kernel(
    const float* __restrict__ nv1, const float* __restrict__ nv2,
    const float* __restrict__ rowsum, float* __restrict__ deg)
{
    const int j = blockIdx.x * 256 + threadIdx.x;
    const int i0 = blockIdx.y * 256;
    float v[R_RANK];
    #pragma unroll
    for (int r = 0; r < R_RANK; ++r) v[r] = nv2[r * NN + j];
    float acc = 0.f;
    for (int i = i0; i < i0 + 256; ++i) {
        float s = 0.f;
        #pragma unroll
        for (int r = 0; r < R_RANK; ++r) s = fmaf(nv1[i * R_RANK + r], v[r], s);
        acc += __expf(fmaxf(s, 0.f)) * (1.0f / rowsum[i]);
    }
    atomicAdd(&deg[j], acc);
}

// ---------------------------------------------------------------------------
// N3: AnT build
// ---------------------------------------------------------------------------
__global__ __launch_bounds__(256) void an_build_kernel(
    const float* __restrict__ nv1, const float* __restrict__ nv2,
    const float* __restrict__ rowsum, const float* __restrict__ deg,
    unsigned short* __restrict__ AnT)
{
    const int tid = threadIdx.x;
    const int j = blockIdx.x * 256 + tid;
    const int i0 = blockIdx.y * 8;
    __shared__ float v2s[8][R_RANK];
    __shared__ float dis[8];
    if (tid < 8 * R_RANK) {
        const int r = tid / 8, t = tid % 8;
        v2s[t][r] = nv2[r * NN + i0 + t];
    }
    if (tid < 8) dis[tid] = rsqrtf(1.0f + deg[i0 + tid]);

    float a[R_RANK];
    #pragma unroll
    for (int r = 0; r < R_RANK; ++r) a[r] = nv1[j * R_RANK + r];
    const float rs = 1.0f / rowsum[j];
    const float dj = rsqrtf(1.0f + deg[j]);
    __syncthreads();

    #pragma unroll
    for (int t = 0; t < 8; ++t) {
        const int i = i0 + t;
        float s = 0.f;
        #pragma unroll
        for (int r = 0; r < R_RANK; ++r) s = fmaf(a[r], v2s[t][r], s);
        const float adp = __expf(fmaxf(s, 0.f)) * rs;
        const float val = (adp + ((i == j) ? 1.f : 0.f)) * dis[t] * dj;
        AnT[(size_t)i * NN + j] = f2bf(val);
    }
}

// ---------------------------------------------------------------------------
// Split-K reduce + epilogue -> bf16. EPI: 0 none, 2 bn(relu(x+b)) col-indexed.
// ---------------------------------------------------------------------------
template<int EPI, int S, int NC>
__global__ __launch_bounds__(256) void reduce_k(
    const float* __restrict__ P, unsigned short* __restrict__ out, const int MN,
    const float* __restrict__ bias, const float* __restrict__ gamma,
    const float* __restrict__ beta, const float* __restrict__ mean,
    const float* __restrict__ var)
{
    const int idx = blockIdx.x * 256 + threadIdx.x;   // float4 index
    const int n4 = MN >> 2;
    const float4* Pv = (const float4*)P;
    float4 v = Pv[idx];
    #pragma unroll
    for (int z = 1; z < S; ++z) {
        const float4 t = Pv[idx + (size_t)z * n4];
        v.x += t.x; v.y += t.y; v.z += t.z; v.w += t.w;
    }
    float vals[4] = {v.x, v.y, v.z, v.w};
    if constexpr (EPI == 2) {
        const int c0 = (idx << 2) & (NC - 1);
        const float4 b4 = *(const float4*)(bias + c0);
        const float4 g4 = *(const float4*)(gamma + c0);
        const float4 e4 = *(const float4*)(beta + c0);
        const float4 m4 = *(const float4*)(mean + c0);
        const float4 v4 = *(const float4*)(var + c0);
        const float bb[4] = {b4.x, b4.y, b4.z, b4.w};
        const float gg[4] = {g4.x, g4.y, g4.z, g4.w};
        const float ee[4] = {e4.x, e4.y, e4.z, e4.w};
        const float mm[4] = {m4.x, m4.y, m4.z, m4.w};
        const float vv[4] = {v4.x, v4.y, v4.z, v4.w};
        #pragma unroll
        for (int j = 0; j < 4; ++j) {
            const float sc = gg[j] * rsqrtf(vv[j] + 1e-5f);
            const float sh = ee[j] - mm[j] * sc;
            vals[j] = fmaf(fmaxf(vals[j] + bb[j], 0.f), sc, sh);
        }
    }
    ushort4 p;
    p.x = f2bf(vals[0]); p.y = f2bf(vals[1]); p.z = f2bf(vals[2]); p.w = f2bf(vals[3]);
    *(ushort4*)(out + ((size_t)idx << 2)) = p;
}

// ---------------------------------------------------------------------------
// N11 (R9-verified): split-K reduce + bn2(relu(x+b)) + mean-pool + last-block
// attention finalize. pooled accessed ONLY via atomics; counter completion.
// ---------------------------------------------------------------------------
template<int S>
__global__ __launch_bounds__(256) void reduce_pool_fin(
    const float* __restrict__ P, float* __restrict__ pooled,
    unsigned int* __restrict__ counter,
    const float* __restrict__ bias, const float* __restrict__ gamma,
    const float* __restrict__ beta, const float* __restrict__ mean,
    const float* __restrict__ var,
    const float* __restrict__ w_attn, const float* __restrict__ b_attn,
    float* __restrict__ out)
{
    const int row = blockIdx.x;    // 0..511
    const int tid = threadIdx.x;
    constexpr int n4 = 512 * 4096 / 4;
    const float4* Pv = (const float4*)P;
    const float b0 = bias[row];
    float s = 0.f;
    #pragma unroll
    for (int c = 0; c < 4; ++c) {
        const int i4 = row * 1024 + c * 256 + tid;
        float4 v = Pv[i4];
        #pragma unroll
        for (int z = 1; z < S; ++z) {
            const float4 t = Pv[i4 + (size_t)z * n4];
            v.x += t.x; v.y += t.y; v.z += t.z; v.w += t.w;
        }
        s += fmaxf(v.x + b0, 0.f) + fmaxf(v.y + b0, 0.f)
           + fmaxf(v.z + b0, 0.f) + fmaxf(v.w + b0, 0.f);
    }
    #pragma unroll
    for (int off = 32; off > 0; off >>= 1) s += __shfl_down(s, off, 64);
    __shared__ float red[4];
    __shared__ int last;
    if ((tid & 63) == 0) red[tid >> 6] = s;
    __syncthreads();
    if (tid == 0) {
        const float tot = red[0] + red[1] + red[2] + red[3];
        const float sc = gamma[row] * rsqrtf(var[row] + 1e-5f);
        const float sh = beta[row] - mean[row] * sc;
        atomicExch(&pooled[row], fmaf(sc, tot * (1.0f / 4096.0f), sh));
        __threadfence();
        last = (atomicAdd(counter, 1u) == 511u);
    }
    __syncthreads();
    if (!last) return;
    __threadfence();
    const float p0 = atomicAdd(&pooled[tid], 0.f);
    const float p1 = atomicAdd(&pooled[tid + 256], 0.f);
    float part = p0 * w_attn[tid] + p1 * w_attn[tid + 256];
    #pragma unroll
    for (int off = 32; off > 0; off >>= 1) part += __shfl_down(part, off, 64);
    __shared__ float red2[4];
    __shared__ float attn_s;
    if ((tid & 63) == 0) red2[tid >> 6] = part;
    __syncthreads();
    if (tid == 0) {
        const float dot = red2[0] + red2[1] + red2[2] + red2[3];
        attn_s = 1.0f / (1.0f + __expf(-(dot + b_attn[0])));
    }
    __syncthreads();
    out[tid] = p0 * attn_s;
    out[tid + 256] = p1 * attn_s;
}

// ---------------------------------------------------------------------------
extern "C" void kernel_launch(void* const* d_in, const int* in_sizes, int n_in,
                              void* d_out, int out_size, void* d_ws, size_t ws_size,
                              hipStream_t stream) {
    const float* x      = (const float*)d_in[0];
    const float* w_map  = (const float*)d_in[1];
    const float* b_map  = (const float*)d_in[2];
    const float* nv1    = (const float*)d_in[3];
    const float* nv2    = (const float*)d_in[4];
    const float* w1     = (const float*)d_in[5];
    const float* b1     = (const float*)d_in[6];
    const float* w2     = (const float*)d_in[7];
    const float* b2     = (const float*)d_in[8];
    const float* bn1_g  = (const float*)d_in[9];
    const float* bn1_b  = (const float*)d_in[10];
    const float* bn1_m  = (const float*)d_in[11];
    const float* bn1_v  = (const float*)d_in[12];
    const float* bn2_g  = (const float*)d_in[13];
    const float* bn2_b  = (const float*)d_in[14];
    const float* bn2_m  = (const float*)d_in[15];
    const float* bn2_v  = (const float*)d_in[16];
    const float* w_attn = (const float*)d_in[17];
    const float* b_attn = (const float*)d_in[18];
    float* out = (float*)d_out;

    // workspace (~85.1 MB), aliasing lifetime-checked (R8/R9 layout):
    const size_t MB = 1024 * 1024;
    char* ws = (char*)d_ws;
    unsigned short* AnT = (unsigned short*)(ws);                  // [0,32M)
    float*          P   = (float*)(ws + 32 * MB);                 // [32M,64M) partials
    char* B0 = ws + 64 * MB;
    unsigned short* xb  = (unsigned short*)(B0);                  // 8 MB, dead after G1
    unsigned short* t1T = (unsigned short*)(B0);                  //   reuse, dead after G3
    unsigned short* t2T = (unsigned short*)(B0);                  //   reuse after G3
    unsigned short* xm  = (unsigned short*)(B0 + 8 * MB);         // 8 MB, dead after G2
    unsigned short* h1  = (unsigned short*)(B0 + 8 * MB);         //   reuse, dead after G4
    unsigned short* wmT = (unsigned short*)(B0 + 16 * MB);        // 2 MB
    unsigned short* w1T = (unsigned short*)(B0 + 18 * MB);        // 2 MB
    unsigned short* w2T = (unsigned short*)(B0 + 20 * MB);        // 1 MB
    float* deg    = (float*)(B0 + 21 * MB);
    float* rowsum = deg + 4096;
    float* pooled = rowsum + 4096;
    unsigned int* counter = (unsigned int*)(pooled + 512);

    // N1: prep | row_stats (zeroes deg + counter)
    prep_rs_kernel<<<dim3(32, 32, 5), 256, 0, stream>>>(
        x, w_map, w1, w2, xb, wmT, w1T, w2T, nv1, nv2, rowsum, deg, counter);
    // N2: col degree
    col_sum_kernel<<<dim3(16, 16), 256, 0, stream>>>(nv1, nv2, rowsum, deg);
    // N3: AnT
    an_build_kernel<<<dim3(16, 512), 256, 0, stream>>>(nv1, nv2, rowsum, deg, AnT);
    // N4: G1 xm = relu(x @ w_map + b)   direct, XM=1 (32,8)
    gemm_mfma<1, 1, 1, 1><<<dim3(32, 8, 1), 256, 0, stream>>>(
        xb, wmT, nullptr, xm, 4096, 1024, 1024, b_map);
    // N5: G2 t1T = (xm @ w1)^T          direct transposed, XM=1
    gemm_mfma<1, 2, 0, 1><<<dim3(32, 8, 1), 256, 0, stream>>>(
        xm, w1T, nullptr, t1T, 4096, 1024, 1024, nullptr);
    // N6: G3 AnT @ t1 partials          SK2, XM=1 (512 blocks; R9: 70.6 us)
    gemm_mfma<2, 0, 0, 1><<<dim3(32, 8, 2), 256, 0, stream>>>(
        AnT, t1T, P, nullptr, 4096, 1024, 4096, nullptr);
    // N7: h1 = bn1(relu(sum + b1))
    reduce_k<2, 2, 1024><<<4096, 256, 0, stream>>>(P, h1, 4194304,
        b1, bn1_g, bn1_b, bn1_m, bn1_v);
    // N8: G4 (swapped) t2 partials = w2T @ h1^T   SK2 (256 blocks)
    gemm_mfma<2, 0, 0, 0><<<dim3(32, 4, 2), 256, 0, stream>>>(
        w2T, h1, P, nullptr, 512, 4096, 1024, nullptr);
    // N9: t2T = sum
    reduce_k<0, 2, 1><<<2048, 256, 0, stream>>>(P, t2T, 2097152,
        nullptr, nullptr, nullptr, nullptr, nullptr);
    // N10: G5 (swapped) h2 partials = t2T @ AnT^T   SK4 (512 blocks)
    gemm_mfma<4, 0, 0, 0><<<dim3(32, 4, 4), 256, 0, stream>>>(
        t2T, AnT, P, nullptr, 512, 4096, 4096, nullptr);
    // N11: bn2 + mean-pool + last-block attention finalize
    reduce_pool_fin<4><<<512, 256, 0, stream>>>(
        P, pooled, counter, b2, bn2_g, bn2_b, bn2_m, bn2_v, w_attn, b_attn, out);
}